// Round 12
// baseline (38.672 us; speedup 1.0000x reference)
//
#include <hip/hip_runtime.h>
#include <hip/hip_bf16.h>

typedef float f32x16 __attribute__((ext_vector_type(16)));
typedef float f32x4v __attribute__((ext_vector_type(4)));

#define GLOBAL_AS(p) ((const __attribute__((address_space(1))) void*)(p))
#define LDS_AS(p)    ((__attribute__((address_space(3))) void*)(p))

#define LP 8192
#define D 128
#define TWOEPS 2e-6f
#define CEPS 1.28e-10f   /* 128 * EPS^2 */
#define MARGIN 0.2f
#define NTRI 2080        /* 64*65/2 lower-triangular 128x128 tiles */
#define NBLK 512         /* blocks 0-31 take a 5th tile */
#define INV_DENOM 1.4903545e-8f  /* 1 / (8192*8191) */

/* LDS per buffer: A tile 16K | B tile 16K */
#define BUFSZ 32768
#define AOFF 0
#define BOFF 16384

// ---------------- Phase A: normalize p rows -> fp8 (row-major), q8[], w[] ----------
// 4 lanes per row, 16 rows per wave. Block 0 zeroes out[0].
__global__ __launch_bounds__(64) void rows_kernel(const float* __restrict__ p,
                                                  const float* __restrict__ n,
                                                  char* __restrict__ pb,
                                                  float* __restrict__ qarr,
                                                  float* __restrict__ warr,
                                                  float* __restrict__ out) {
    const int lane = threadIdx.x;
    if (blockIdx.x == 0 && lane == 0) out[0] = 0.0f;
    const int sub = lane & 3;    // quarter of the row (32 floats)
    const int r = lane >> 2;     // 0..15
    const int row = blockIdx.x * 16 + r;

    const float4* px = (const float4*)(p + (size_t)row * D + sub * 32);
    const float4* nx = (const float4*)(n + sub * 32);  // n row 0 (t=0)
    float4 x[8], y[8];
#pragma unroll
    for (int k = 0; k < 8; ++k) { x[k] = px[k]; y[k] = nx[k]; }

    float ssp = 0.0f, ssn = 0.0f;
#pragma unroll
    for (int k = 0; k < 8; ++k) {
        ssp += fmaf(x[k].x, x[k].x, fmaf(x[k].y, x[k].y,
               fmaf(x[k].z, x[k].z, x[k].w * x[k].w)));
        ssn += fmaf(y[k].x, y[k].x, fmaf(y[k].y, y[k].y,
               fmaf(y[k].z, y[k].z, y[k].w * y[k].w)));
    }
    ssp += __shfl_xor(ssp, 1); ssp += __shfl_xor(ssp, 2);
    ssn += __shfl_xor(ssn, 1); ssn += __shfl_xor(ssn, 2);

    const float invp = 1.0f / fmaxf(sqrtf(ssp), 1e-12f);
    const float invn = 1.0f / fmaxf(sqrtf(ssn), 1e-12f);

    float s = 0.0f, q = 0.0f, dn = 0.0f, sn = 0.0f, qn = 0.0f, q8 = 0.0f;
    int pk8[8];
#pragma unroll
    for (int k = 0; k < 8; ++k) {
        float a0 = x[k].x * invp, a1 = x[k].y * invp,
              a2 = x[k].z * invp, a3 = x[k].w * invp;
        float h0 = y[k].x * invn, h1 = y[k].y * invn,
              h2 = y[k].z * invn, h3 = y[k].w * invn;
        s  += (a0 + a1) + (a2 + a3);
        q  += fmaf(a0, a0, fmaf(a1, a1, fmaf(a2, a2, a3 * a3)));
        dn += fmaf(a0, h0, fmaf(a1, h1, fmaf(a2, h2, a3 * h3)));
        sn += (h0 + h1) + (h2 + h3);
        qn += fmaf(h0, h0, fmaf(h1, h1, fmaf(h2, h2, h3 * h3)));
        int wlo = __builtin_amdgcn_cvt_pk_fp8_f32(a0, a1, 0, false);
        int wfl = __builtin_amdgcn_cvt_pk_fp8_f32(a2, a3, wlo, true);
        pk8[k] = wfl;
        float b0 = __builtin_amdgcn_cvt_f32_fp8(wfl, 0);
        float b1 = __builtin_amdgcn_cvt_f32_fp8(wfl, 1);
        float b2 = __builtin_amdgcn_cvt_f32_fp8(wfl, 2);
        float b3 = __builtin_amdgcn_cvt_f32_fp8(wfl, 3);
        q8 += fmaf(b0, b0, fmaf(b1, b1, fmaf(b2, b2, b3 * b3)));
    }
    char* dst = pb + (size_t)row * 128 + sub * 32;
    ((int4*)dst)[0] = make_int4(pk8[0], pk8[1], pk8[2], pk8[3]);
    ((int4*)dst)[1] = make_int4(pk8[4], pk8[5], pk8[6], pk8[7]);

#pragma unroll
    for (int m = 1; m < 4; m <<= 1) {
        s += __shfl_xor(s, m);
        q += __shfl_xor(q, m);
        dn += __shfl_xor(dn, m);
        sn += __shfl_xor(sn, m);
        qn += __shfl_xor(qn, m);
        q8 += __shfl_xor(q8, m);
    }
    if (sub == 0) {
        float sq = q + qn - 2.0f * dn + TWOEPS * (s - sn) + CEPS;
        float dpn = sqrtf(fmaxf(sq, 0.0f));
        qarr[row] = q8;
        warr[row] = MARGIN - dpn;
    }
}

// ---------------- Phase B: R6-champion pair kernel, lighter epilogue ---------------
// Persistent 512 blocks x 4-5 tiles, double-buffered 128x128 LDS tiles staged by
// global_load_lds (4 loads/wave/tile), counted vmcnt(4). Epilogue scalars read
// directly from global (L1/L2-hot) -- no qw staging, no LDS unpack.
__global__ __launch_bounds__(512, 4) void pair_kernel(const char* __restrict__ pb,
                                                      const float* __restrict__ qarr,
                                                      const float* __restrict__ warr,
                                                      float* __restrict__ out) {
    __shared__ __align__(16) char smem[2 * BUFSZ];  // 64 KB -> 2 blocks/CU
    const int blk = blockIdx.x;
    const int tid = threadIdx.x;
    const int wave = tid >> 6, lane = tid & 63;
    const int nt = (blk < NTRI - 4 * NBLK) ? 5 : 4;  // 32 blocks take a 5th tile

    const int wr = wave >> 2, wc = wave & 3;  // 2x4 waves, 64x32 output each
    const int ln31 = lane & 31;
    const int h = lane >> 5;

    auto decode = [](int b, int& ti, int& tj) {
        int t = (int)((__builtin_amdgcn_sqrtf(8.0f * (float)b + 1.0f) - 1.0f) * 0.5f);
        while ((t + 1) * (t + 2) / 2 <= b) ++t;
        while (t * (t + 1) / 2 > b) --t;
        ti = t;
        tj = b - t * (t + 1) / 2;
    };

    auto stage = [&](int ti, int tj, char* buf) {
        const char* gA = pb + (size_t)ti * 16384;
        const char* gB = pb + (size_t)tj * 16384;  // diag: same src, both copies
#pragma unroll
        for (int r = 0; r < 2; ++r) {
            int obase = wave * 2048 + r * 1024;  // wave-uniform LDS byte base
            int o = obase + lane * 16;
            int src = o ^ (((o >> 7) & 7) << 4);  // inverse swizzle on global side
            __builtin_amdgcn_global_load_lds(GLOBAL_AS(gA + src),
                                             LDS_AS(buf + AOFF + obase), 16, 0, 0);
            __builtin_amdgcn_global_load_lds(GLOBAL_AS(gB + src),
                                             LDS_AS(buf + BOFF + obase), 16, 0, 0);
        }
    };

    int ti0, tj0;
    decode(blk, ti0, tj0);
    stage(ti0, tj0, smem);  // prologue: tile 0 -> buf 0 (4 loads in flight)
    int icur = blk;
    bool diag_cur = (ti0 == tj0);
    bool diag_nxt = false;

    float la0 = 0.0f, la1 = 0.0f, lb0 = 0.0f, lb1 = 0.0f;

    for (int t = 0; t < nt; ++t) {
        char* cur = smem + (size_t)(t & 1) * BUFSZ;
        char* nxt = smem + (size_t)((t + 1) & 1) * BUFSZ;

        int ti, tj;
        decode(icur, ti, tj);

        if (t + 1 < nt) {
            int ti1, tj1;
            decode(icur + NBLK, ti1, tj1);
            diag_nxt = (ti1 == tj1);
            stage(ti1, tj1, nxt);  // 4 more loads -> outstanding <= 8
            asm volatile("s_waitcnt vmcnt(4)" ::: "memory");  // cur's 4 done
        } else {
            asm volatile("s_waitcnt vmcnt(0)" ::: "memory");
        }
        __builtin_amdgcn_s_barrier();        // all waves' cur slices landed
        __builtin_amdgcn_sched_barrier(0);

        // Epilogue scalars straight from global (independent of LDS/MFMA; the
        // compiler schedules these loads under the MFMA block).
        const int i0 = ti * 128, j0 = tj * 128;
        const int j = j0 + wc * 32 + ln31;
        const float qj = qarr[j];
        const float wj = warr[j];
        f32x4v q4[2][4], w4[2][4];
#pragma unroll
        for (int mt = 0; mt < 2; ++mt)
#pragma unroll
            for (int g = 0; g < 4; ++g) {
                int rbase = i0 + wr * 64 + mt * 32 + 8 * g + 4 * h;
                q4[mt][g] = *(const f32x4v*)(qarr + rbase);
                w4[mt][g] = *(const f32x4v*)(warr + rbase);
            }

        const char* lA = cur + AOFF;
        const char* lB = cur + BOFF;

        f32x16 acc0 = {}, acc1 = {};
#pragma unroll
        for (int ks = 0; ks < 8; ++ks) {
            int co = ((ks ^ (ln31 & 7)) << 4) + h * 8;
            long bv  = *(const long*)(lB + (wc * 32 + ln31) * 128 + co);
            long av0 = *(const long*)(lA + (wr * 64 + ln31) * 128 + co);
            long av1 = *(const long*)(lA + (wr * 64 + 32 + ln31) * 128 + co);
            acc0 = __builtin_amdgcn_mfma_f32_32x32x16_fp8_fp8(av0, bv, acc0, 0, 0, 0);
            acc1 = __builtin_amdgcn_mfma_f32_32x32x16_fp8_fp8(av1, bv, acc1, 0, 0, 0);
        }

        // C/D 32x32 layout: col = ln31, row = (reg&3) + 8*(reg>>2) + 4*h.
        if (diag_cur) {
#pragma unroll
            for (int g = 0; g < 4; ++g)
#pragma unroll
                for (int r2 = 0; r2 < 4; ++r2) {
                    float sq0 = fmaf(-2.0f, acc0[g * 4 + r2], q4[0][g][r2] + qj);
                    float sq1 = fmaf(-2.0f, acc1[g * 4 + r2], q4[1][g][r2] + qj);
                    float d0 = __builtin_amdgcn_sqrtf(fmaxf(sq0, 0.0f));  // i==j -> ~0
                    float d1 = __builtin_amdgcn_sqrtf(fmaxf(sq1, 0.0f));
                    la0 += fmaxf(d0 + w4[0][g][r2], 0.0f);
                    la1 += fmaxf(d1 + w4[1][g][r2], 0.0f);
                }
        } else {
#pragma unroll
            for (int g = 0; g < 4; ++g)
#pragma unroll
                for (int r2 = 0; r2 < 4; ++r2) {
                    float sq0 = fmaf(-2.0f, acc0[g * 4 + r2], q4[0][g][r2] + qj);
                    float sq1 = fmaf(-2.0f, acc1[g * 4 + r2], q4[1][g][r2] + qj);
                    float d0 = __builtin_amdgcn_sqrtf(sq0);  // off-diag: sq >= ~0.9
                    float d1 = __builtin_amdgcn_sqrtf(sq1);
                    la0 += fmaxf(d0 + w4[0][g][r2], 0.0f);   // term (i,j)
                    la1 += fmaxf(d1 + w4[1][g][r2], 0.0f);
                    lb0 += fmaxf(d0 + wj, 0.0f);             // term (j,i)
                    lb1 += fmaxf(d1 + wj, 0.0f);
                }
        }
        __builtin_amdgcn_s_barrier();  // reads of cur done before it is re-staged
        diag_cur = diag_nxt;
        icur += NBLK;
    }

    // block reduction + one atomic per block
    float local = (la0 + la1) + (lb0 + lb1);
#pragma unroll
    for (int m = 1; m < 64; m <<= 1) local += __shfl_xor(local, m);
    float* sred = (float*)smem;
    if (lane == 0) sred[wave] = local;
    __syncthreads();
    if (tid == 0) {
        float t0 = (sred[0] + sred[1]) + (sred[2] + sred[3]);
        float t1 = (sred[4] + sred[5]) + (sred[6] + sred[7]);
        atomicAdd(out, (t0 + t1) * INV_DENOM);
    }
}

extern "C" void kernel_launch(void* const* d_in, const int* in_sizes, int n_in,
                              void* d_out, int out_size, void* d_ws, size_t ws_size,
                              hipStream_t stream) {
    const float* p = (const float*)d_in[0];  // [8192,128] f32
    const float* n = (const float*)d_in[1];  // [64,128] f32
    float* out = (float*)d_out;
    char* ws = (char*)d_ws;

    char*  pb   = ws;                                       // 1 MB (8192 x 128 B fp8)
    float* qarr = (float*)(ws + (1u << 20));                // 32 KB
    float* warr = (float*)(ws + (1u << 20) + (32u << 10));  // 32 KB

    hipLaunchKernelGGL(rows_kernel, dim3(LP / 16), dim3(64), 0, stream, p, n, pb,
                       qarr, warr, out);
    hipLaunchKernelGGL(pair_kernel, dim3(NBLK), dim3(512), 0, stream, pb, qarr,
                       warr, out);
}

// Round 13
// 30.988 us; speedup vs baseline: 1.2480x; 1.2480x over previous
//
#include <hip/hip_runtime.h>
#include <hip/hip_bf16.h>

typedef float f32x16 __attribute__((ext_vector_type(16)));
typedef float f32x4v __attribute__((ext_vector_type(4)));
typedef float f32x2 __attribute__((ext_vector_type(2)));

#define GLOBAL_AS(p) ((const __attribute__((address_space(1))) void*)(p))
#define LDS_AS(p)    ((__attribute__((address_space(3))) void*)(p))

#define LP 8192
#define D 128
#define TWOEPS 2e-6f
#define CEPS 1.28e-10f   /* 128 * EPS^2 */
#define MARGIN 0.2f
#define NTRI 2080        /* 64*65/2 lower-triangular 128x128 tiles */
#define NBLK 1024        /* blocks 0-31 take a 3rd tile */
#define INV_DENOM 1.4903545e-8f  /* 1 / (8192*8191) */

/* LDS per buffer: A 16K | B 16K | scalars 2K (qi 512 | wi 512 | qj 512 | wj 512) */
#define BUFSZ 34816
#define AOFF 0
#define BOFF 16384
#define QWOFF 32768

// ---------------- Phase A: normalize p rows -> fp8, q8[], w[] ----------------------
// 4 lanes per row, 16 rows per wave, 512 blocks x 64 threads.
__global__ __launch_bounds__(64) void rows_kernel(const float* __restrict__ p,
                                                  const float* __restrict__ n,
                                                  char* __restrict__ pb,
                                                  float* __restrict__ qarr,
                                                  float* __restrict__ warr) {
    const int lane = threadIdx.x;
    const int sub = lane & 3;    // quarter of the row (32 floats)
    const int r = lane >> 2;     // 0..15
    const int row = blockIdx.x * 16 + r;

    const float4* px = (const float4*)(p + (size_t)row * D + sub * 32);
    const float4* nx = (const float4*)(n + sub * 32);  // n row 0 (t=0)
    float4 x[8], y[8];
#pragma unroll
    for (int k = 0; k < 8; ++k) { x[k] = px[k]; y[k] = nx[k]; }

    float ssp = 0.0f, ssn = 0.0f;
#pragma unroll
    for (int k = 0; k < 8; ++k) {
        ssp += fmaf(x[k].x, x[k].x, fmaf(x[k].y, x[k].y,
               fmaf(x[k].z, x[k].z, x[k].w * x[k].w)));
        ssn += fmaf(y[k].x, y[k].x, fmaf(y[k].y, y[k].y,
               fmaf(y[k].z, y[k].z, y[k].w * y[k].w)));
    }
    ssp += __shfl_xor(ssp, 1); ssp += __shfl_xor(ssp, 2);
    ssn += __shfl_xor(ssn, 1); ssn += __shfl_xor(ssn, 2);

    const float invp = 1.0f / fmaxf(sqrtf(ssp), 1e-12f);
    const float invn = 1.0f / fmaxf(sqrtf(ssn), 1e-12f);

    float s = 0.0f, q = 0.0f, dn = 0.0f, sn = 0.0f, qn = 0.0f, q8 = 0.0f;
    int pk8[8];
#pragma unroll
    for (int k = 0; k < 8; ++k) {
        float a0 = x[k].x * invp, a1 = x[k].y * invp,
              a2 = x[k].z * invp, a3 = x[k].w * invp;
        float h0 = y[k].x * invn, h1 = y[k].y * invn,
              h2 = y[k].z * invn, h3 = y[k].w * invn;
        s  += (a0 + a1) + (a2 + a3);
        q  += fmaf(a0, a0, fmaf(a1, a1, fmaf(a2, a2, a3 * a3)));
        dn += fmaf(a0, h0, fmaf(a1, h1, fmaf(a2, h2, a3 * h3)));
        sn += (h0 + h1) + (h2 + h3);
        qn += fmaf(h0, h0, fmaf(h1, h1, fmaf(h2, h2, h3 * h3)));
        int wlo = __builtin_amdgcn_cvt_pk_fp8_f32(a0, a1, 0, false);
        int wfl = __builtin_amdgcn_cvt_pk_fp8_f32(a2, a3, wlo, true);
        pk8[k] = wfl;
        float b0 = __builtin_amdgcn_cvt_f32_fp8(wfl, 0);
        float b1 = __builtin_amdgcn_cvt_f32_fp8(wfl, 1);
        float b2 = __builtin_amdgcn_cvt_f32_fp8(wfl, 2);
        float b3 = __builtin_amdgcn_cvt_f32_fp8(wfl, 3);
        q8 += fmaf(b0, b0, fmaf(b1, b1, fmaf(b2, b2, b3 * b3)));
    }
    char* dst = pb + (size_t)row * 128 + sub * 32;
    ((int4*)dst)[0] = make_int4(pk8[0], pk8[1], pk8[2], pk8[3]);
    ((int4*)dst)[1] = make_int4(pk8[4], pk8[5], pk8[6], pk8[7]);

#pragma unroll
    for (int m = 1; m < 4; m <<= 1) {
        s += __shfl_xor(s, m);
        q += __shfl_xor(q, m);
        dn += __shfl_xor(dn, m);
        sn += __shfl_xor(sn, m);
        qn += __shfl_xor(qn, m);
        q8 += __shfl_xor(q8, m);
    }
    if (sub == 0) {
        float sq = q + qn - 2.0f * dn + TWOEPS * (s - sn) + CEPS;
        float dpn = sqrtf(fmaxf(sq, 0.0f));
        qarr[row] = q8;
        warr[row] = MARGIN - dpn;
    }
}

// ---------------- Phase B: 4-wave 64x64-wave-tile pair kernel ----------------------
// R6 skeleton (dbuf LDS, gload_lds + XOR swizzle, counted vmcnt, 2 barriers/tile)
// with: 4 waves/block each owning a 64x64 output (fragment reads per output
// -40%), scalars q/w staged to LDS per tile, packed-f32 (v_pk_*) epilogue.
__global__ __launch_bounds__(256, 2) void pair_kernel(const char* __restrict__ pb,
                                                      const float* __restrict__ qarr,
                                                      const float* __restrict__ warr,
                                                      float* __restrict__ partials) {
    __shared__ __align__(16) char smem[2 * BUFSZ];  // 68 KB -> 2 blocks/CU
    const int blk = blockIdx.x;
    const int tid = threadIdx.x;
    const int wave = tid >> 6, lane = tid & 63;
    const int nt = (blk < NTRI - 2 * NBLK) ? 3 : 2;  // 32 blocks take a 3rd tile

    const int wr = wave >> 1, wc = wave & 1;  // 2x2 waves, 64x64 output each
    const int ln31 = lane & 31;
    const int h = lane >> 5;

    auto decode = [](int b, int& ti, int& tj) {
        int t = (int)((__builtin_amdgcn_sqrtf(8.0f * (float)b + 1.0f) - 1.0f) * 0.5f);
        while ((t + 1) * (t + 2) / 2 <= b) ++t;
        while (t * (t + 1) / 2 > b) --t;
        ti = t;
        tj = b - t * (t + 1) / 2;
    };

    // 10 loads/wave/tile: 4 A-rounds + 4 B-rounds + 2 scalar rounds
    auto stage = [&](int ti, int tj, char* buf) {
        const char* gA = pb + (size_t)ti * 16384;
        const char* gB = pb + (size_t)tj * 16384;  // diag: same src, both copies
#pragma unroll
        for (int r = 0; r < 4; ++r) {
            int obase = r * 4096 + wave * 1024;  // wave-uniform LDS byte base
            int o = obase + lane * 16;
            int src = o ^ (((o >> 7) & 7) << 4);  // inverse swizzle on global side
            __builtin_amdgcn_global_load_lds(GLOBAL_AS(gA + src),
                                             LDS_AS(buf + AOFF + obase), 16, 0, 0);
            __builtin_amdgcn_global_load_lds(GLOBAL_AS(gB + src),
                                             LDS_AS(buf + BOFF + obase), 16, 0, 0);
        }
        // scalar arrays: wave a stages array a (qi, wi, qj, wj), 512 B in 2 rounds
        const float* sa = (wave == 0) ? (qarr + ti * 128)
                        : (wave == 1) ? (warr + ti * 128)
                        : (wave == 2) ? (qarr + tj * 128)
                                      : (warr + tj * 128);
#pragma unroll
        for (int h2 = 0; h2 < 2; ++h2)
            __builtin_amdgcn_global_load_lds(GLOBAL_AS(sa + h2 * 64 + lane),
                                             LDS_AS(buf + QWOFF + wave * 512 + h2 * 256),
                                             4, 0, 0);
    };

    int ti0, tj0;
    decode(blk, ti0, tj0);
    stage(ti0, tj0, smem);  // prologue: tile 0 -> buf 0 (10 loads in flight)
    int icur = blk;
    bool diag_cur = (ti0 == tj0);
    bool diag_nxt = false;

    f32x2 la0 = {0.0f, 0.0f}, la1 = {0.0f, 0.0f};
    f32x2 lb0 = {0.0f, 0.0f}, lb1 = {0.0f, 0.0f};
    const f32x2 zero2 = {0.0f, 0.0f};

    for (int t = 0; t < nt; ++t) {
        char* cur = smem + (size_t)(t & 1) * BUFSZ;
        char* nxt = smem + (size_t)((t + 1) & 1) * BUFSZ;

        if (t + 1 < nt) {
            int ti1, tj1;
            decode(icur + NBLK, ti1, tj1);
            diag_nxt = (ti1 == tj1);
            stage(ti1, tj1, nxt);  // 10 more loads -> outstanding <= 20
            asm volatile("s_waitcnt vmcnt(10)" ::: "memory");  // cur's 10 done
        } else {
            asm volatile("s_waitcnt vmcnt(0)" ::: "memory");
        }
        __builtin_amdgcn_s_barrier();        // all waves' cur slices landed
        __builtin_amdgcn_sched_barrier(0);

        const char* lA = cur + AOFF;
        const char* lB = cur + BOFF;
        const float* qil = (const float*)(cur + QWOFF);
        const float* wil = (const float*)(cur + QWOFF + 512);
        const float* qjl = (const float*)(cur + QWOFF + 1024);
        const float* wjl = (const float*)(cur + QWOFF + 1536);

        f32x16 acc00 = {}, acc01 = {}, acc10 = {}, acc11 = {};
#pragma unroll
        for (int ks = 0; ks < 8; ++ks) {
            int co = ((ks ^ (ln31 & 7)) << 4) + h * 8;
            long bv0 = *(const long*)(lB + (wc * 64 + ln31) * 128 + co);
            long bv1 = *(const long*)(lB + (wc * 64 + 32 + ln31) * 128 + co);
            long av0 = *(const long*)(lA + (wr * 64 + ln31) * 128 + co);
            long av1 = *(const long*)(lA + (wr * 64 + 32 + ln31) * 128 + co);
            acc00 = __builtin_amdgcn_mfma_f32_32x32x16_fp8_fp8(av0, bv0, acc00, 0, 0, 0);
            acc01 = __builtin_amdgcn_mfma_f32_32x32x16_fp8_fp8(av0, bv1, acc01, 0, 0, 0);
            acc10 = __builtin_amdgcn_mfma_f32_32x32x16_fp8_fp8(av1, bv0, acc10, 0, 0, 0);
            acc11 = __builtin_amdgcn_mfma_f32_32x32x16_fp8_fp8(av1, bv1, acc11, 0, 0, 0);
        }

        // Epilogue (packed f32). C/D 32x32: col = ln31, row = (reg&3)+8*(reg>>2)+4h.
        const int jb0 = wc * 64 + ln31;       // local col for nt=0
        const f32x2 qj0 = {qjl[jb0], qjl[jb0]};
        const f32x2 wj0 = {wjl[jb0], wjl[jb0]};
        const f32x2 qj1 = {qjl[jb0 + 32], qjl[jb0 + 32]};
        const f32x2 wj1 = {wjl[jb0 + 32], wjl[jb0 + 32]};

#define EPI_PAIR(ACC, QJ, WJ, LA, LB_, MT)                                          \
        {                                                                           \
            _Pragma("unroll") for (int g = 0; g < 4; ++g) {                         \
                int rbase = wr * 64 + (MT) * 32 + 8 * g + 4 * h;                    \
                f32x4v qi4 = *(const f32x4v*)(qil + rbase);                         \
                f32x4v wi4 = *(const f32x4v*)(wil + rbase);                         \
                _Pragma("unroll") for (int pr = 0; pr < 2; ++pr) {                  \
                    f32x2 ap = {ACC[g * 4 + 2 * pr], ACC[g * 4 + 2 * pr + 1]};      \
                    f32x2 qip = {qi4[2 * pr], qi4[2 * pr + 1]};                     \
                    f32x2 wip = {wi4[2 * pr], wi4[2 * pr + 1]};                     \
                    f32x2 sq = (qip + QJ) - 2.0f * ap;                              \
                    if (diag_cur) sq = __builtin_elementwise_max(sq, zero2);        \
                    f32x2 d;                                                        \
                    d.x = __builtin_amdgcn_sqrtf(sq.x);                             \
                    d.y = __builtin_amdgcn_sqrtf(sq.y);                             \
                    LA += __builtin_elementwise_max(d + wip, zero2);                \
                    if (!diag_cur) LB_ += __builtin_elementwise_max(d + WJ, zero2); \
                }                                                                   \
            }                                                                       \
        }
        EPI_PAIR(acc00, qj0, wj0, la0, lb0, 0)
        EPI_PAIR(acc01, qj1, wj1, la0, lb0, 0)
        EPI_PAIR(acc10, qj0, wj0, la1, lb1, 1)
        EPI_PAIR(acc11, qj1, wj1, la1, lb1, 1)
#undef EPI_PAIR

        __builtin_amdgcn_s_barrier();  // reads of cur done before it is re-staged
        diag_cur = diag_nxt;
        icur += NBLK;
    }

    // block reduction
    float local = (la0.x + la0.y) + (la1.x + la1.y) + (lb0.x + lb0.y) + (lb1.x + lb1.y);
#pragma unroll
    for (int m = 1; m < 64; m <<= 1) local += __shfl_xor(local, m);
    float* sred = (float*)smem;
    if (lane == 0) sred[wave] = local;
    __syncthreads();
    if (tid == 0)
        partials[blk] = (sred[0] + sred[1]) + (sred[2] + sred[3]);
}

// ---------------- Phase C: final reduce ----------------
__global__ void reduce_kernel(const float* __restrict__ partials, float* __restrict__ out,
                              int npart) {
    __shared__ float sred[4];
    float s = 0.0f;
    for (int t = threadIdx.x; t < npart; t += 256) s += partials[t];
#pragma unroll
    for (int m = 1; m < 64; m <<= 1) s += __shfl_xor(s, m);
    int wave = threadIdx.x >> 6, lane = threadIdx.x & 63;
    if (lane == 0) sred[wave] = s;
    __syncthreads();
    if (threadIdx.x == 0) {
        float tot = (sred[0] + sred[1]) + (sred[2] + sred[3]);
        out[0] = fmaxf(tot * INV_DENOM, 0.0f);
    }
}

extern "C" void kernel_launch(void* const* d_in, const int* in_sizes, int n_in,
                              void* d_out, int out_size, void* d_ws, size_t ws_size,
                              hipStream_t stream) {
    const float* p = (const float*)d_in[0];  // [8192,128] f32
    const float* n = (const float*)d_in[1];  // [64,128] f32
    float* out = (float*)d_out;
    char* ws = (char*)d_ws;

    char*  pb    = ws;                                       // 1 MB (8192 x 128 B fp8)
    float* qarr  = (float*)(ws + (1u << 20));                // 32 KB
    float* warr  = (float*)(ws + (1u << 20) + (32u << 10));  // 32 KB
    float* parts = (float*)(ws + (1u << 20) + (64u << 10));  // NBLK floats

    hipLaunchKernelGGL(rows_kernel, dim3(LP / 16), dim3(64), 0, stream, p, n, pb,
                       qarr, warr);
    hipLaunchKernelGGL(pair_kernel, dim3(NBLK), dim3(256), 0, stream, pb, qarr,
                       warr, parts);
    hipLaunchKernelGGL(reduce_kernel, dim3(1), dim3(256), 0, stream, parts, out, NBLK);
}